// Round 10
// baseline (850.932 us; speedup 1.0000x reference)
//
#include <hip/hip_runtime.h>
#include <hip/hip_bf16.h>
#include <math.h>

#define NN 50000
#define NE 1600000
#define D 128
#define NRBF 50
#define RCUT 5.0f
#define LNEPS 1e-5f
#define SCAN_B 196   // ceil(50000/256)
#define NB 16
#define NPW 8        // nodes per wave in gather
#define EO_GRID 2048
#define NPASS 4      // d-passes; 128/4 = 32 cols -> 3.2MB quarter-table fits 4MiB L2

typedef __attribute__((ext_vector_type(8))) short bf16x8;
typedef __attribute__((ext_vector_type(4))) float f32x4;
typedef __attribute__((ext_vector_type(2))) float f32x2;

__device__ __forceinline__ float silu_f(float x) {
    return x / (1.0f + __expf(-x));
}
__device__ __forceinline__ unsigned short f2bf(float x) {
    __hip_bfloat16 b = __float2bfloat16(x);
    return *reinterpret_cast<unsigned short*>(&b);
}
__device__ __forceinline__ float bf2f(unsigned short u) {
    unsigned int x = ((unsigned int)u) << 16;
    return __uint_as_float(x);
}

// ---------------------------------------------------------------- nbr
__global__ __launch_bounds__(128) void nbr_kernel(
    const float* __restrict__ z, const float* __restrict__ Aw,
    const float* __restrict__ Ab, unsigned short* __restrict__ nbr_bf)
{
    const int n = blockIdx.x;
    const int d = threadIdx.x;
    float acc = Ab[d];
#pragma unroll
    for (int k = 0; k < 25; ++k)
        acc = fmaf(z[n * 25 + k], Aw[k * D + d], acc);
    nbr_bf[(size_t)n * D + d] = f2bf(silu_f(acc));
}

// ---------------------------------------------------------------- aux + count
__global__ __launch_bounds__(256) void aux_kernel(
    const int* __restrict__ edge, const float* __restrict__ r,
    const float* __restrict__ u, float* __restrict__ rt0,
    float* __restrict__ rt1, float* __restrict__ rt2,
    float* __restrict__ cout, int* __restrict__ cnt)
{
    const int e = blockIdx.x * 256 + threadIdx.x;
    if (e >= NE) return;
    const float rr = r[e];
    __builtin_nontemporal_store(rr, &rt0[e]);
    const float cc = (rr < RCUT)
        ? 0.5f * (__cosf(3.14159265358979f * rr * (1.0f / RCUT)) + 1.0f)
        : 0.0f;
    __builtin_nontemporal_store(cc, &cout[e]);
    const float x  = u[e * 3 + 0];
    const float y  = u[e * 3 + 1];
    const float zc = u[e * 3 + 2];
    __builtin_nontemporal_store(x,  &rt1[(size_t)e * 3 + 0]);
    __builtin_nontemporal_store(y,  &rt1[(size_t)e * 3 + 1]);
    __builtin_nontemporal_store(zc, &rt1[(size_t)e * 3 + 2]);
    const float s3 = 1.7320508075688772f;
    __builtin_nontemporal_store(s3 * x * y,                  &rt2[(size_t)e * 5 + 0]);
    __builtin_nontemporal_store(s3 * y * zc,                 &rt2[(size_t)e * 5 + 1]);
    __builtin_nontemporal_store(0.5f * (3.0f * zc * zc - 1.0f), &rt2[(size_t)e * 5 + 2]);
    __builtin_nontemporal_store(s3 * zc * x,                 &rt2[(size_t)e * 5 + 3]);
    __builtin_nontemporal_store(0.5f * s3 * (x * x - y * y), &rt2[(size_t)e * 5 + 4]);
    atomicAdd(&cnt[edge[2 * e]], 1);
}

// ---------------------------------------------------------------- scans
__global__ __launch_bounds__(256) void scan1_kernel(
    const int* __restrict__ cnt, int* __restrict__ off, int* __restrict__ bsum)
{
    __shared__ int s[2][256];
    const int t = threadIdx.x;
    const int g = blockIdx.x * 256 + t;
    const int v = (g < NN) ? cnt[g] : 0;
    int incl = v;
    s[0][t] = incl;
    __syncthreads();
    int cur = 0;
#pragma unroll
    for (int dd = 1; dd < 256; dd <<= 1) {
        const int add = (t >= dd) ? s[cur][t - dd] : 0;
        incl += add;
        s[cur ^ 1][t] = incl;
        __syncthreads();
        cur ^= 1;
    }
    if (g < NN) off[g] = incl - v;
    if (t == 255) bsum[blockIdx.x] = incl;
}

__global__ __launch_bounds__(256) void scan2_kernel(int* __restrict__ bsum)
{
    __shared__ int s[2][256];
    const int t = threadIdx.x;
    const int v = (t < SCAN_B) ? bsum[t] : 0;
    int incl = v;
    s[0][t] = incl;
    __syncthreads();
    int cur = 0;
#pragma unroll
    for (int dd = 1; dd < 256; dd <<= 1) {
        const int add = (t >= dd) ? s[cur][t - dd] : 0;
        incl += add;
        s[cur ^ 1][t] = incl;
        __syncthreads();
        cur ^= 1;
    }
    if (t < SCAN_B) bsum[t] = incl - v;
}

__global__ __launch_bounds__(256) void scan3_kernel(
    int* __restrict__ off, const int* __restrict__ bsum)
{
    const int g = blockIdx.x * 256 + threadIdx.x;
    if (g < NN) off[g] += bsum[blockIdx.x];
    if (g == 0) off[NN] = NE;
}

// ---------------------------------------------------------------- scatter {j, r}
__global__ __launch_bounds__(256) void scatter_kernel(
    const int* __restrict__ edge, const float* __restrict__ r,
    const int* __restrict__ off, int* __restrict__ cursor,
    uint2* __restrict__ jr)
{
    const int e = blockIdx.x * 256 + threadIdx.x;
    if (e >= NE) return;
    const int2 ep = ((const int2*)edge)[e];
    const int pos = atomicAdd(&cursor[ep.x], 1);
    uint2 v;
    v.x = (unsigned int)ep.y;
    v.y = __float_as_uint(r[e]);
    jr[off[ep.x] + pos] = v;
}

// ---------------------------------------------------------------- gather msg
// d-sliced pass kernel: handles cols [pass*32, pass*32+32). The nbr quarter-
// table (3.2MB) is L2-resident per XCD -> gathers are L2 hits.
// col map within pass: col = pass*32 + lr*2 + dt (dt 0..1) so one 4B gather
// feeds both MFMA col-tiles.
__global__ __launch_bounds__(256, 4) void gather_msg_wave(
    const uint2* __restrict__ jr, const int* __restrict__ off,
    const float* __restrict__ W_ndp, const float* __restrict__ b_ndp,
    const unsigned short* __restrict__ nbr_bf, float* __restrict__ m,
    const int pass)
{
    const int tid = threadIdx.x;
    const int w   = tid >> 6;
    const int l   = tid & 63;
    const int lr  = l & 15;
    const int lg  = l >> 4;
    const int c0  = pass * 32 + lr * 2;

    bf16x8 wf[2][2];
#pragma unroll
    for (int dt = 0; dt < 2; ++dt) {
        const int col = c0 + dt;
#pragma unroll
        for (int s = 0; s < 2; ++s) {
            bf16x8 v;
#pragma unroll
            for (int j = 0; j < 8; ++j) {
                const int k = s * 32 + lg * 8 + j;
                float wv = 0.0f;
                if (k < NRBF)       wv = W_ndp[k * D + col];
                else if (k == NRBF) wv = b_ndp[col];
                v[j] = (short)f2bf(wv);
            }
            wf[dt][s] = v;
        }
    }

    const float start = expf(-RCUT);
    const float step  = (1.0f - start) / (NRBF - 1);
    const float bq    = (2.0f / NRBF) * (1.0f - start);
    const float beta  = 1.0f / (bq * bq);

    const int wid = blockIdx.x * 4 + w;

    for (int nn = 0; nn < NPW; ++nn) {
        const int n = wid * NPW + nn;
        if (n >= NN) break;
        const int s0  = off[n];
        const int deg = off[n + 1] - s0;

        f32x4 macc0 = {0, 0, 0, 0};
        f32x4 macc1 = {0, 0, 0, 0};

        // prologue: head for batch 0
        uint2 v = make_uint2(0u, 0u);
        if (l < 16 && l < deg) v = jr[s0 + l];

        for (int base = 0; base < deg; base += 16) {
            const bool val = (l < 16) && (base + l < deg);
            const unsigned int jv = val ? v.x : 0u;
            float er = 0.0f, cc = 0.0f;
            if (val) {
                const float rr = __uint_as_float(v.y);
                er = __expf(-rr);
                cc = (rr < RCUT)
                    ? 0.5f * (__cosf(3.14159265358979f * rr * (1.0f / RCUT)) + 1.0f)
                    : 0.0f;
            }
            // prefetch next head
            uint2 vn = make_uint2(0u, 0u);
            if (l < 16 && base + 16 + l < deg) vn = jr[s0 + base + 16 + l];

            const float erL = __shfl(er, lr);
            const float ccL = __shfl(cc, lr);

            // issue the 4 random 4B nbr gathers (L2-resident quarter rows)
            unsigned int nv0, nv1, nv2, nv3;
            {
                const int j0 = __shfl((int)jv, lg * 4 + 0);
                const int j1 = __shfl((int)jv, lg * 4 + 1);
                const int j2 = __shfl((int)jv, lg * 4 + 2);
                const int j3 = __shfl((int)jv, lg * 4 + 3);
                nv0 = *(const unsigned int*)(nbr_bf + (size_t)j0 * D + c0);
                nv1 = *(const unsigned int*)(nbr_bf + (size_t)j1 * D + c0);
                nv2 = *(const unsigned int*)(nbr_bf + (size_t)j2 * D + c0);
                nv3 = *(const unsigned int*)(nbr_bf + (size_t)j3 * D + c0);
            }

            // A-fragments in registers (c-scaled rbf; bias row k=50)
            bf16x8 af[2];
#pragma unroll
            for (int s = 0; s < 2; ++s) {
                bf16x8 a;
#pragma unroll
                for (int j = 0; j < 8; ++j) {
                    const int k = s * 32 + lg * 8 + j;
                    float pv = 0.0f;
                    if (k < NRBF) {
                        const float diff = erL - (start + (float)k * step);
                        pv = ccL * __expf(-beta * diff * diff);
                    } else if (k == NRBF) {
                        pv = ccL;
                    }
                    a[j] = (short)f2bf(pv);
                }
                af[s] = a;
            }

            f32x4 acc0 = {0, 0, 0, 0};
            acc0 = __builtin_amdgcn_mfma_f32_16x16x32_bf16(af[0], wf[0][0], acc0, 0, 0, 0);
            acc0 = __builtin_amdgcn_mfma_f32_16x16x32_bf16(af[1], wf[0][1], acc0, 0, 0, 0);
            f32x4 acc1 = {0, 0, 0, 0};
            acc1 = __builtin_amdgcn_mfma_f32_16x16x32_bf16(af[0], wf[1][0], acc1, 0, 0, 0);
            acc1 = __builtin_amdgcn_mfma_f32_16x16x32_bf16(af[1], wf[1][1], acc1, 0, 0, 0);

            macc0[0] = fmaf(bf2f((unsigned short)(nv0 & 0xffff)), acc0[0], macc0[0]);
            macc1[0] = fmaf(bf2f((unsigned short)(nv0 >> 16)),    acc1[0], macc1[0]);
            macc0[1] = fmaf(bf2f((unsigned short)(nv1 & 0xffff)), acc0[1], macc0[1]);
            macc1[1] = fmaf(bf2f((unsigned short)(nv1 >> 16)),    acc1[1], macc1[1]);
            macc0[2] = fmaf(bf2f((unsigned short)(nv2 & 0xffff)), acc0[2], macc0[2]);
            macc1[2] = fmaf(bf2f((unsigned short)(nv2 >> 16)),    acc1[2], macc1[2]);
            macc0[3] = fmaf(bf2f((unsigned short)(nv3 & 0xffff)), acc0[3], macc0[3]);
            macc1[3] = fmaf(bf2f((unsigned short)(nv3 >> 16)),    acc1[3], macc1[3]);

            v = vn;
        }

        float v0 = macc0[0] + macc0[1] + macc0[2] + macc0[3];
        float v1 = macc1[0] + macc1[1] + macc1[2] + macc1[3];
        v0 += __shfl_xor(v0, 16); v0 += __shfl_xor(v0, 32);
        v1 += __shfl_xor(v1, 16); v1 += __shfl_xor(v1, 32);
        if (lg == 0) {
            f32x2 o = {v0, v1};
            *(f32x2*)&m[(size_t)n * D + c0] = o;
        }
    }
}

// ---------------------------------------------------------------- node MLP
__global__ __launch_bounds__(256) void node_kernel2(
    const float* __restrict__ z, const float* __restrict__ A_na_w,
    const float* __restrict__ A_na_b, const float* __restrict__ m,
    const float* __restrict__ W_nrd_w, const float* __restrict__ W_nrd_b,
    const float* __restrict__ W_nru_w, const float* __restrict__ W_nru_b,
    const float* __restrict__ ln_g, const float* __restrict__ ln_b,
    float* __restrict__ hout, unsigned short* __restrict__ h_bf)
{
    __shared__ float inbuf[NB][260];
    __shared__ float wbuf[32][128];
    __shared__ float part[4][NB][2];

    const int tid = threadIdx.x;
    const int n0 = blockIdx.x * NB;
    const int nl = tid & 15;
    const int dg = tid >> 4;

    for (int idx = tid; idx < NB * 128; idx += 256) {
        const int n = idx >> 7;
        const int d = idx & 127;
        float acc = A_na_b[d];
#pragma unroll
        for (int k = 0; k < 25; ++k)
            acc = fmaf(z[(size_t)(n0 + n) * 25 + k], A_na_w[k * D + d], acc);
        inbuf[n][d]       = silu_f(acc);
        inbuf[n][128 + d] = m[(size_t)(n0 + n) * D + d];
    }

    float h1[8];
#pragma unroll
    for (int dd = 0; dd < 8; ++dd) h1[dd] = W_nrd_b[dg * 8 + dd];

    for (int tile = 0; tile < 8; ++tile) {
        __syncthreads();
        for (int v = tid; v < 32 * 32; v += 256) {
            const int row = v >> 5;
            const int c4  = (v & 31) * 4;
            *(float4*)&wbuf[row][c4] =
                *(const float4*)&W_nrd_w[(size_t)(tile * 32 + row) * D + c4];
        }
        __syncthreads();
#pragma unroll 4
        for (int k = 0; k < 32; ++k) {
            const float rin = inbuf[nl][tile * 32 + k];
            const float4 wa = *(const float4*)&wbuf[k][dg * 8];
            const float4 wb = *(const float4*)&wbuf[k][dg * 8 + 4];
            h1[0] = fmaf(rin, wa.x, h1[0]);
            h1[1] = fmaf(rin, wa.y, h1[1]);
            h1[2] = fmaf(rin, wa.z, h1[2]);
            h1[3] = fmaf(rin, wa.w, h1[3]);
            h1[4] = fmaf(rin, wb.x, h1[4]);
            h1[5] = fmaf(rin, wb.y, h1[5]);
            h1[6] = fmaf(rin, wb.z, h1[6]);
            h1[7] = fmaf(rin, wb.w, h1[7]);
        }
    }

    float s = 0.0f, sq = 0.0f;
#pragma unroll
    for (int dd = 0; dd < 8; ++dd) { s += h1[dd]; sq += h1[dd] * h1[dd]; }
    s  += __shfl_xor(s, 16);  sq += __shfl_xor(sq, 16);
    s  += __shfl_xor(s, 32);  sq += __shfl_xor(sq, 32);
    const int wv = tid >> 6;
    if ((tid & 63) < 16) { part[wv][nl][0] = s; part[wv][nl][1] = sq; }
    __syncthreads();
    float ts = 0.0f, tsq = 0.0f;
#pragma unroll
    for (int w = 0; w < 4; ++w) { ts += part[w][nl][0]; tsq += part[w][nl][1]; }
    const float mu  = ts * (1.0f / 128.0f);
    const float var = tsq * (1.0f / 128.0f) - mu * mu;
    const float inv = rsqrtf(var + LNEPS);

#pragma unroll
    for (int dd = 0; dd < 8; ++dd) {
        const int d = dg * 8 + dd;
        inbuf[nl][d] = silu_f((h1[dd] - mu) * inv * ln_g[d] + ln_b[d]);
    }

    float h2[8];
#pragma unroll
    for (int dd = 0; dd < 8; ++dd) h2[dd] = W_nru_b[dg * 8 + dd];

    for (int tile = 0; tile < 4; ++tile) {
        __syncthreads();
        for (int v = tid; v < 32 * 32; v += 256) {
            const int row = v >> 5;
            const int c4  = (v & 31) * 4;
            *(float4*)&wbuf[row][c4] =
                *(const float4*)&W_nru_w[(size_t)(tile * 32 + row) * D + c4];
        }
        __syncthreads();
#pragma unroll 4
        for (int k = 0; k < 32; ++k) {
            const float rin = inbuf[nl][tile * 32 + k];
            const float4 wa = *(const float4*)&wbuf[k][dg * 8];
            const float4 wb = *(const float4*)&wbuf[k][dg * 8 + 4];
            h2[0] = fmaf(rin, wa.x, h2[0]);
            h2[1] = fmaf(rin, wa.y, h2[1]);
            h2[2] = fmaf(rin, wa.z, h2[2]);
            h2[3] = fmaf(rin, wa.w, h2[3]);
            h2[4] = fmaf(rin, wb.x, h2[4]);
            h2[5] = fmaf(rin, wb.y, h2[5]);
            h2[6] = fmaf(rin, wb.z, h2[6]);
            h2[7] = fmaf(rin, wb.w, h2[7]);
        }
    }

    f32x4 o0 = {h2[0], h2[1], h2[2], h2[3]};
    f32x4 o1 = {h2[4], h2[5], h2[6], h2[7]};
    float* hp = &hout[(size_t)(n0 + nl) * D + dg * 8];
    __builtin_nontemporal_store(o0, (f32x4*)hp);
    __builtin_nontemporal_store(o1, (f32x4*)(hp + 4));

    unsigned int b0 = (unsigned int)f2bf(h2[0]) | ((unsigned int)f2bf(h2[1]) << 16);
    unsigned int b1 = (unsigned int)f2bf(h2[2]) | ((unsigned int)f2bf(h2[3]) << 16);
    unsigned int b2 = (unsigned int)f2bf(h2[4]) | ((unsigned int)f2bf(h2[5]) << 16);
    unsigned int b3 = (unsigned int)f2bf(h2[6]) | ((unsigned int)f2bf(h2[7]) << 16);
    *(uint4*)&h_bf[(size_t)(n0 + nl) * D + dg * 8] = make_uint4(b0, b1, b2, b3);
}

// ---------------------------------------------------------------- edge out
// d-sliced pass kernel: cols [pass*32, pass*32+32); h quarter-table (3.2MB)
// is L2-resident -> both random gathers become L2 hits. Same 2-stage head
// pipeline as before. col map: col = pass*32 + lr*2 + dt.
__global__ __launch_bounds__(256, 4) void edge_out_wave(
    const int* __restrict__ edge, const float* __restrict__ r,
    const float* __restrict__ W_erp, const float* __restrict__ b_erp,
    const unsigned short* __restrict__ h_bf, float* __restrict__ t,
    const int pass)
{
    const int tid = threadIdx.x;
    const int w   = tid >> 6;
    const int l   = tid & 63;
    const int lr  = l & 15;
    const int lg  = l >> 4;
    const int c0  = pass * 32 + lr * 2;

    bf16x8 wf[2][2];
    float bias[2];
#pragma unroll
    for (int dt = 0; dt < 2; ++dt) {
        const int col = c0 + dt;
        bias[dt] = b_erp[col];
#pragma unroll
        for (int s = 0; s < 2; ++s) {
            bf16x8 v;
#pragma unroll
            for (int j = 0; j < 8; ++j) {
                const int k = s * 32 + lg * 8 + j;
                v[j] = (k < NRBF) ? (short)f2bf(W_erp[k * D + col]) : (short)0;
            }
            wf[dt][s] = v;
        }
    }

    const float start = expf(-RCUT);
    const float step  = (1.0f - start) / (NRBF - 1);
    const float bq    = (2.0f / NRBF) * (1.0f - start);
    const float beta  = 1.0f / (bq * bq);

    const int wid = blockIdx.x * 4 + w;
    const int nw  = gridDim.x * 4;
    const int ngroup = NE / 16;

    // prologue head
    int2 ep = make_int2(0, 0);
    float rv = 0.0f;
    if (wid < ngroup && l < 16) {
        ep = ((const int2*)edge)[wid * 16 + l];
        rv = r[wid * 16 + l];
    }

    for (int g = wid; g < ngroup; g += nw) {
        const int iv = ep.x;
        const int jv = ep.y;
        const float er = __expf(-rv);

        // prefetch next head
        int2 epn = make_int2(0, 0);
        float rvn = 0.0f;
        if (g + nw < ngroup && l < 16) {
            epn = ((const int2*)edge)[(g + nw) * 16 + l];
            rvn = r[(g + nw) * 16 + l];
        }

        const float erL = __shfl(er, lr);

        // issue the 8 random 4B h gathers (L2-resident quarter rows)
        unsigned int hi0, hi1, hi2, hi3, hj0, hj1, hj2, hj3;
        {
            const int i0 = __shfl(iv, lg * 4 + 0), j0 = __shfl(jv, lg * 4 + 0);
            const int i1 = __shfl(iv, lg * 4 + 1), j1 = __shfl(jv, lg * 4 + 1);
            const int i2 = __shfl(iv, lg * 4 + 2), j2 = __shfl(jv, lg * 4 + 2);
            const int i3 = __shfl(iv, lg * 4 + 3), j3 = __shfl(jv, lg * 4 + 3);
            hi0 = *(const unsigned int*)(h_bf + (size_t)i0 * D + c0);
            hj0 = *(const unsigned int*)(h_bf + (size_t)j0 * D + c0);
            hi1 = *(const unsigned int*)(h_bf + (size_t)i1 * D + c0);
            hj1 = *(const unsigned int*)(h_bf + (size_t)j1 * D + c0);
            hi2 = *(const unsigned int*)(h_bf + (size_t)i2 * D + c0);
            hj2 = *(const unsigned int*)(h_bf + (size_t)j2 * D + c0);
            hi3 = *(const unsigned int*)(h_bf + (size_t)i3 * D + c0);
            hj3 = *(const unsigned int*)(h_bf + (size_t)j3 * D + c0);
        }

        // A-fragments (rbf only)
        bf16x8 af[2];
#pragma unroll
        for (int s = 0; s < 2; ++s) {
            bf16x8 a;
#pragma unroll
            for (int j = 0; j < 8; ++j) {
                const int k = s * 32 + lg * 8 + j;
                float pv = 0.0f;
                if (k < NRBF) {
                    const float diff = erL - (start + (float)k * step);
                    pv = __expf(-beta * diff * diff);
                }
                a[j] = (short)f2bf(pv);
            }
            af[s] = a;
        }

        f32x4 acc0 = {0, 0, 0, 0};
        acc0 = __builtin_amdgcn_mfma_f32_16x16x32_bf16(af[0], wf[0][0], acc0, 0, 0, 0);
        acc0 = __builtin_amdgcn_mfma_f32_16x16x32_bf16(af[1], wf[0][1], acc0, 0, 0, 0);
        f32x4 acc1 = {0, 0, 0, 0};
        acc1 = __builtin_amdgcn_mfma_f32_16x16x32_bf16(af[0], wf[1][0], acc1, 0, 0, 0);
        acc1 = __builtin_amdgcn_mfma_f32_16x16x32_bf16(af[1], wf[1][1], acc1, 0, 0, 0);

        const int eb = g * 16;
#pragma unroll
        for (int q = 0; q < 4; ++q) {
            const unsigned int hiq = (q == 0) ? hi0 : (q == 1) ? hi1 : (q == 2) ? hi2 : hi3;
            const unsigned int hjq = (q == 0) ? hj0 : (q == 1) ? hj1 : (q == 2) ? hj2 : hj3;
            const float hv0 = bf2f((unsigned short)(hiq & 0xffff))
                            + bf2f((unsigned short)(hjq & 0xffff));
            const float hv1 = bf2f((unsigned short)(hiq >> 16))
                            + bf2f((unsigned short)(hjq >> 16));
            f32x2 o = {hv0 * (acc0[q] + bias[0]), hv1 * (acc1[q] + bias[1])};
            float* tp = &t[(size_t)(eb + lg * 4 + q) * D + c0];
            __builtin_nontemporal_store(o, (f32x2*)tp);
        }

        ep = epn;
        rv = rvn;
    }
}

// ---------------------------------------------------------------- launch
extern "C" void kernel_launch(void* const* d_in, const int* in_sizes, int n_in,
                              void* d_out, int out_size, void* d_ws, size_t ws_size,
                              hipStream_t stream) {
    const float* z      = (const float*)d_in[0];
    const int*   edge   = (const int*)d_in[1];
    const float* r      = (const float*)d_in[2];
    const float* u      = (const float*)d_in[3];
    const float* A_na_w  = (const float*)d_in[4];
    const float* A_na_b  = (const float*)d_in[5];
    const float* A_nbr_w = (const float*)d_in[6];
    const float* A_nbr_b = (const float*)d_in[7];
    const float* W_ndp_w = (const float*)d_in[8];
    const float* W_ndp_b = (const float*)d_in[9];
    const float* W_nrd_w = (const float*)d_in[10];
    const float* W_nrd_b = (const float*)d_in[11];
    const float* W_nru_w = (const float*)d_in[12];
    const float* W_nru_b = (const float*)d_in[13];
    const float* W_erp_w = (const float*)d_in[14];
    const float* W_erp_b = (const float*)d_in[15];
    const float* ln_g    = (const float*)d_in[16];
    const float* ln_b    = (const float*)d_in[17];

    float* out = (float*)d_out;
    float* h_out   = out;
    float* t_out   = out + (size_t)NN * D;
    float* rt0_out = t_out + (size_t)NE * D;
    float* rt1_out = rt0_out + (size_t)NE;
    float* rt2_out = rt1_out + (size_t)NE * 3;
    float* c_out   = rt2_out + (size_t)NE * 5;

    // ws: nbr_bf (12.8MB) | m f32 (25.6MB) | h_bf (12.8MB)
    unsigned short* nbr_bf = (unsigned short*)d_ws;
    float* m_ws   = (float*)((char*)d_ws + (size_t)NN * D * sizeof(unsigned short));
    unsigned short* h_bf = (unsigned short*)((char*)m_ws + (size_t)NN * D * sizeof(float));

    // CSR scratch in the t region (819MB): consumed by gather_msg, which
    // finishes before edge_out overwrites t (stream order).
    uint2* jr   = (uint2*)t_out;                 // NE uint2 (12.8 MB)
    int* off    = (int*)(jr + NE);               // NN+1
    int* cursor = off + (NN + 1);                // NN
    int* bsum   = cursor + NN;                   // 256

    hipMemsetAsync(cursor, 0, (size_t)NN * sizeof(int), stream);

    nbr_kernel<<<NN, 128, 0, stream>>>(z, A_nbr_w, A_nbr_b, nbr_bf);

    aux_kernel<<<(NE + 255) / 256, 256, 0, stream>>>(
        edge, r, u, rt0_out, rt1_out, rt2_out, c_out, cursor);

    scan1_kernel<<<SCAN_B, 256, 0, stream>>>(cursor, off, bsum);
    scan2_kernel<<<1, 256, 0, stream>>>(bsum);
    scan3_kernel<<<SCAN_B, 256, 0, stream>>>(off, bsum);

    hipMemsetAsync(cursor, 0, (size_t)NN * sizeof(int), stream);

    scatter_kernel<<<(NE + 255) / 256, 256, 0, stream>>>(edge, r, off, cursor, jr);

    {
        const int nwaves = (NN + NPW - 1) / NPW;          // 6250
        const int blocks = (nwaves + 3) / 4;              // 1563
        for (int pass = 0; pass < NPASS; ++pass)
            gather_msg_wave<<<blocks, 256, 0, stream>>>(
                jr, off, W_ndp_w, W_ndp_b, nbr_bf, m_ws, pass);
    }

    node_kernel2<<<NN / NB, 256, 0, stream>>>(
        z, A_na_w, A_na_b, m_ws, W_nrd_w, W_nrd_b,
        W_nru_w, W_nru_b, ln_g, ln_b, h_out, h_bf);

    for (int pass = 0; pass < NPASS; ++pass)
        edge_out_wave<<<EO_GRID, 256, 0, stream>>>(
            edge, r, W_erp_w, W_erp_b, h_bf, t_out, pass);
}